// Round 6
// baseline (280.112 us; speedup 1.0000x reference)
//
#include <hip/hip_runtime.h>
#include <stdint.h>
#include <math.h>

typedef __bf16 bf16;
typedef __bf16 bf16x4 __attribute__((ext_vector_type(4)));
typedef __bf16 bf16x8 __attribute__((ext_vector_type(8)));
typedef float floatx4 __attribute__((ext_vector_type(4)));

#define CEXP 0.1803368801111204f  /* (1/8) * log2(e) */

// async global->LDS, 16B/lane; LDS dest = wave-uniform base + lane*16.
__device__ __forceinline__ void async_copy16(const bf16* g, bf16* l) {
  __builtin_amdgcn_global_load_lds(
      (const __attribute__((address_space(1))) unsigned int*)g,
      (__attribute__((address_space(3))) unsigned int*)l, 16, 0, 0);
}

// ---------------------------------------------------------------------------
// Weight pre-convert: fp32 [1024][1024] -> bf16, 4 matrices (Wq,Wk,Wv,Wo)
// ---------------------------------------------------------------------------
__global__ __launch_bounds__(256) void wcvt_kernel(
    const float* __restrict__ Wq, const float* __restrict__ Wk,
    const float* __restrict__ Wv, const float* __restrict__ Wo,
    bf16* __restrict__ dst)
{
  const float* src = (blockIdx.y == 0) ? Wq : (blockIdx.y == 1) ? Wk
                   : (blockIdx.y == 2) ? Wv : Wo;
  bf16* d = dst + (size_t)blockIdx.y * 1048576;
  const int i = (blockIdx.x * 256 + threadIdx.x) * 4;
  const floatx4 v = *(const floatx4*)(src + i);
  bf16x4 o;
#pragma unroll
  for (int j = 0; j < 4; ++j) o[j] = (bf16)v[j];
  *(bf16x4*)(d + i) = o;
}

// ---------------------------------------------------------------------------
// GEMM: C[4096,1024] = A(fp32) @ Wb(bf16)^T + bias(fp32)
// 128x128 tile, BK=64, 4 waves. A: register-prefetch + cvt -> LDS (stride 72).
// W: async global_load_lds (width 16) into double-buffered Bs (stride 64) —
// loads stay in flight across the whole MFMA phase.
// mode 0: C bf16 [b,h,s,dk] | mode 2: C bf16 [b,h,dk,s] | mode 1: A gathered
// from fp32 scores [b,h,s,dk], C fp32 [token][col]
// ---------------------------------------------------------------------------
__device__ __forceinline__ void gemm_body(
    const float* __restrict__ A, const bf16* __restrict__ Wb,
    const float* __restrict__ bias, void* __restrict__ Cout, const int mode,
    const float oscale)
{
  __shared__ __align__(16) bf16 As[128 * 72];
  __shared__ __align__(16) bf16 Bs[2][128 * 64];
  const int tid  = threadIdx.x;
  const int wave = tid >> 6;
  const int lane = tid & 63;
  const int mlane = lane & 15;
  const int quad  = lane >> 4;
  const int m0 = blockIdx.y * 128;
  const int n0 = blockIdx.x * 128;
  const int wm = (wave >> 1) * 64;
  const int wn = (wave & 1) * 64;
  const int arow = tid >> 4, ac4 = (tid & 15) * 4;  // A: 16 rows/pass, 8 passes
  const int lrow = lane >> 3, lk8 = (lane & 7) * 8; // W async chunk addressing

  floatx4 a_pf[8];

  auto load_a = [&](int k0) {
#pragma unroll
    for (int rr = 0; rr < 8; ++rr) {
      const int row = rr * 16 + arow;
      const float* ga;
      if (mode == 1) {
        const int token = m0 + row;
        const int b = token >> 11, s = token & 2047;
        const int h = k0 >> 6;  // BK=64 stays within one head
        ga = A + (((size_t)(b * 16 + h) * 2048 + s) << 6) + ac4;
      } else {
        ga = A + (size_t)(m0 + row) * 1024 + k0 + ac4;
      }
      a_pf[rr] = *(const floatx4*)ga;
    }
  };
  auto stage_w = [&](int k0, int buf) {
#pragma unroll
    for (int c = 0; c < 4; ++c) {
      const int chunk = wave * 4 + c;            // 16 chunks of 8 rows x 64
      async_copy16(Wb + (size_t)(n0 + chunk * 8 + lrow) * 1024 + k0 + lk8,
                   &Bs[buf][chunk * 512 + lane * 8]);
    }
  };

  load_a(0);
  stage_w(0, 0);

  floatx4 acc[4][4] = {};
  int buf = 0;

  for (int k0 = 0; k0 < 1024; k0 += 64, buf ^= 1) {
    // store A prefetch (cvt fp32->bf16)
#pragma unroll
    for (int rr = 0; rr < 8; ++rr) {
      bf16x4 ac;
#pragma unroll
      for (int j = 0; j < 4; ++j) ac[j] = (bf16)a_pf[rr][j];
      *(bf16x4*)&As[(rr * 16 + arow) * 72 + ac4] = ac;
    }
    __syncthreads();  // drains async W(k0) + A stores visible

    if (k0 + 64 < 1024) { load_a(k0 + 64); stage_w(k0 + 64, buf ^ 1); }

#pragma unroll
    for (int kk = 0; kk < 64; kk += 32) {
      bf16x8 af[4], bfr[4];
#pragma unroll
      for (int t = 0; t < 4; ++t) {
        af[t]  = *(const bf16x8*)&As[(wm + t * 16 + mlane) * 72 + kk + quad * 8];
        bfr[t] = *(const bf16x8*)&Bs[buf][(wn + t * 16 + mlane) * 64 + kk + quad * 8];
      }
#pragma unroll
      for (int mt = 0; mt < 4; ++mt)
#pragma unroll
        for (int nt = 0; nt < 4; ++nt)
          acc[mt][nt] = __builtin_amdgcn_mfma_f32_16x16x32_bf16(
              af[mt], bfr[nt], acc[mt][nt], 0, 0, 0);
    }
    __syncthreads();
  }

  // epilogue
#pragma unroll
  for (int nt = 0; nt < 4; ++nt) {
    const int col = n0 + wn + nt * 16 + mlane;
    const float bv = bias[col];
#pragma unroll
    for (int mt = 0; mt < 4; ++mt) {
#pragma unroll
      for (int r = 0; r < 4; ++r) {
        const int row = m0 + wm + mt * 16 + quad * 4 + r;
        const float v = (acc[mt][nt][r] + bv) * oscale;
        if (mode == 0) {
          const int b = row >> 11, s = row & 2047;
          const int h = col >> 6, dk = col & 63;
          ((bf16*)Cout)[(((size_t)(b * 16 + h) * 2048 + s) << 6) + dk] = (bf16)v;
        } else if (mode == 2) {
          const int b = row >> 11, s = row & 2047;
          const int h = col >> 6, dk = col & 63;
          ((bf16*)Cout)[(((size_t)(b * 16 + h) * 64 + dk) << 11) + s] = (bf16)v;
        } else {
          ((float*)Cout)[(size_t)row * 1024 + col] = v;
        }
      }
    }
  }
}

__global__ __launch_bounds__(256) void qkv_kernel(
    const float* __restrict__ q, const float* __restrict__ k, const float* __restrict__ v,
    const bf16* __restrict__ Wb,
    const float* __restrict__ bq, const float* __restrict__ bk, const float* __restrict__ bv,
    bf16* __restrict__ Qw, bf16* __restrict__ Kw, bf16* __restrict__ Vw)
{
  const int z = blockIdx.z;
  const float* A = (z == 0) ? q : (z == 1) ? k : v;
  const bf16* W  = Wb + (size_t)z * 1048576;
  const float* B = (z == 0) ? bq : (z == 1) ? bk : bv;
  if (z == 2)      gemm_body(A, W, B, Vw, 2, 1.0f);
  else if (z == 1) gemm_body(A, W, B, Kw, 0, 1.0f);
  else             gemm_body(A, W, B, Qw, 0, CEXP);  // softmax scale folded into Q
}

__global__ __launch_bounds__(256) void out_kernel(
    const float* __restrict__ scores, const bf16* __restrict__ Wob,
    const float* __restrict__ bo, float* __restrict__ out)
{
  gemm_body(scores, Wob, bo, out, 1, 1.0f);
}

// ---------------------------------------------------------------------------
// Flash attention, no-max softmax. Block = 128 q x 64-key tiles, 4 waves;
// each wave owns 32 q (2 subtiles of 16) so the 8 K-frag and 8 V-frag LDS
// reads per tile are reused across 2x the MACs (LDS traffic /1.57).
// S^T = K Q^T (operand-swap): per-lane q = mlane, keys consecutive -> b64 P
// stores, per-lane row sums. Q pre-scaled by CEXP. V pre-transposed [b,h,dk,s].
// ---------------------------------------------------------------------------
__global__ __launch_bounds__(256) void attn_kernel(
    const bf16* __restrict__ Qw, const bf16* __restrict__ Kw,
    const bf16* __restrict__ Vtg, float* __restrict__ scores)
{
  __shared__ __align__(16) bf16 Ks[64 * 72];    // [key][dk]
  __shared__ __align__(16) bf16 Vt[64 * 72];    // [dk][key]
  __shared__ __align__(16) bf16 Ps[4][32 * 72]; // per-wave P [q(32)][key]

  const int tid  = threadIdx.x;
  const int wave = tid >> 6;
  const int lane = tid & 63;
  const int mlane = lane & 15;
  const int quad  = lane >> 4;
  const int bh = blockIdx.y;            // 0..31
  const int q0 = blockIdx.x * 128;
  const size_t base = (size_t)bh << 17; // bh * 2048 * 64

  const int srow = tid >> 3, sc8 = (tid & 7) * 8;

  // Q B-frags (loop-invariant): qf[qt][c], q = q0 + wave*32 + qt*16 + mlane
  bf16x8 qf[2][2];
#pragma unroll
  for (int qt = 0; qt < 2; ++qt)
#pragma unroll
    for (int c = 0; c < 2; ++c)
      qf[qt][c] = *(const bf16x8*)
          &Qw[base + (size_t)(q0 + wave * 32 + qt * 16 + mlane) * 64 + c * 32 + quad * 8];

  float rs[2] = {0.f, 0.f};
  floatx4 o[2][4] = {};  // [qt][d-tile]; row=q(quad*4+r), col=d(nt*16+mlane)

  bf16x8 kpf[2], vpf[2];
  auto load_kv = [&](int kt) {
#pragma unroll
    for (int rr = 0; rr < 2; ++rr) {
      const int row = rr * 32 + srow;  // key idx for K, dk idx for V
      kpf[rr] = *(const bf16x8*)&Kw[base + (size_t)(kt + row) * 64 + sc8];
      vpf[rr] = *(const bf16x8*)&Vtg[base + (size_t)row * 2048 + kt + sc8];
    }
  };
  load_kv(0);

  for (int kt = 0; kt < 2048; kt += 64) {
    __syncthreads();  // previous tile's LDS reads complete
#pragma unroll
    for (int rr = 0; rr < 2; ++rr) {
      const int row = rr * 32 + srow;
      *(bf16x8*)&Ks[row * 72 + sc8] = kpf[rr];
      *(bf16x8*)&Vt[row * 72 + sc8] = vpf[rr];
    }
    __syncthreads();
    if (kt + 64 < 2048) load_kv(kt + 64);

    // S^T = K Q^T per key-tile nt; K-frags shared across both q-subtiles
#pragma unroll
    for (int nt = 0; nt < 4; ++nt) {
      bf16x8 a0 = *(const bf16x8*)&Ks[(nt * 16 + mlane) * 72 + quad * 8];
      bf16x8 a1 = *(const bf16x8*)&Ks[(nt * 16 + mlane) * 72 + 32 + quad * 8];
      floatx4 s0 = {}, s1 = {};
      s0 = __builtin_amdgcn_mfma_f32_16x16x32_bf16(a0, qf[0][0], s0, 0, 0, 0);
      s0 = __builtin_amdgcn_mfma_f32_16x16x32_bf16(a1, qf[0][1], s0, 0, 0, 0);
      s1 = __builtin_amdgcn_mfma_f32_16x16x32_bf16(a0, qf[1][0], s1, 0, 0, 0);
      s1 = __builtin_amdgcn_mfma_f32_16x16x32_bf16(a1, qf[1][1], s1, 0, 0, 0);

      bf16x4 pk0, pk1;
#pragma unroll
      for (int r = 0; r < 4; ++r) {
        const float p0 = exp2f(s0[r]);
        const float p1 = exp2f(s1[r]);
        rs[0] += p0; rs[1] += p1;
        pk0[r] = (bf16)p0; pk1[r] = (bf16)p1;
      }
      *(bf16x4*)&Ps[wave][(mlane)      * 72 + nt * 16 + quad * 4] = pk0;
      *(bf16x4*)&Ps[wave][(16 + mlane) * 72 + nt * 16 + quad * 4] = pk1;
    }

    // make this wave's P stores visible before fragment reads
    asm volatile("s_waitcnt lgkmcnt(0)" ::: "memory");

    // O += P V : V-frags shared across both q-subtiles
#pragma unroll
    for (int c = 0; c < 2; ++c) {
      bf16x8 pa0 = *(const bf16x8*)&Ps[wave][(mlane)      * 72 + c * 32 + quad * 8];
      bf16x8 pa1 = *(const bf16x8*)&Ps[wave][(16 + mlane) * 72 + c * 32 + quad * 8];
#pragma unroll
      for (int nt = 0; nt < 4; ++nt) {
        bf16x8 vb = *(const bf16x8*)&Vt[(nt * 16 + mlane) * 72 + c * 32 + quad * 8];
        o[0][nt] = __builtin_amdgcn_mfma_f32_16x16x32_bf16(pa0, vb, o[0][nt], 0, 0, 0);
        o[1][nt] = __builtin_amdgcn_mfma_f32_16x16x32_bf16(pa1, vb, o[1][nt], 0, 0, 0);
      }
    }
  }

  // finalize l(q) per subtile: reduce the 4 quad-partials
#pragma unroll
  for (int qt = 0; qt < 2; ++qt) {
    rs[qt] += __shfl_xor(rs[qt], 16, 64);
    rs[qt] += __shfl_xor(rs[qt], 32, 64);
  }
  const float inv0 = 1.0f / rs[0];
  const float inv1 = 1.0f / rs[1];

  // scores[b,h,s,dk] = O / l ; o rows are q=quad*4+r -> fetch inv from lane q
#pragma unroll
  for (int qt = 0; qt < 2; ++qt) {
#pragma unroll
    for (int r = 0; r < 4; ++r) {
      const float invr = __shfl(qt ? inv1 : inv0, quad * 4 + r, 64);
      const int row = q0 + wave * 32 + qt * 16 + quad * 4 + r;
#pragma unroll
      for (int nt = 0; nt < 4; ++nt)
        scores[base + (size_t)row * 64 + nt * 16 + mlane] = o[qt][nt][r] * invr;
    }
  }
}

// ---------------------------------------------------------------------------
extern "C" void kernel_launch(void* const* d_in, const int* in_sizes, int n_in,
                              void* d_out, int out_size, void* d_ws, size_t ws_size,
                              hipStream_t stream) {
  const float* query = (const float*)d_in[0];
  const float* key   = (const float*)d_in[1];
  const float* value = (const float*)d_in[2];
  const float* Wq = (const float*)d_in[3];
  const float* bq = (const float*)d_in[4];
  const float* Wk = (const float*)d_in[5];
  const float* bk = (const float*)d_in[6];
  const float* Wv = (const float*)d_in[7];
  const float* bv = (const float*)d_in[8];
  const float* Wo = (const float*)d_in[9];
  const float* bo = (const float*)d_in[10];

  float* out    = (float*)d_out;
  float* scores = out + (size_t)4194304;   // second output (fp32)

  bf16* Wb  = (bf16*)d_ws;                 // 4 x 1Mi bf16 = 8 MB (Wq,Wk,Wv,Wo)
  bf16* Qws = Wb + (size_t)4194304;        // [b,h,s,dk], pre-scaled by CEXP
  bf16* Kws = Qws + (size_t)4194304;       // [b,h,s,dk]
  bf16* Vws = Kws + (size_t)4194304;       // [b,h,dk,s] (transposed)

  wcvt_kernel<<<dim3(1024, 4), 256, 0, stream>>>(Wq, Wk, Wv, Wo, Wb);
  qkv_kernel<<<dim3(8, 32, 3), 256, 0, stream>>>(query, key, value, Wb,
                                                 bq, bk, bv, Qws, Kws, Vws);
  attn_kernel<<<dim3(16, 32), 256, 0, stream>>>(Qws, Kws, Vws, scores);
  out_kernel<<<dim3(8, 32), 256, 0, stream>>>(scores, Wb + (size_t)3145728, bo, out);
}

// Round 7
// 247.802 us; speedup vs baseline: 1.1304x; 1.1304x over previous
//
#include <hip/hip_runtime.h>
#include <stdint.h>
#include <math.h>

typedef __bf16 bf16;
typedef __bf16 bf16x4 __attribute__((ext_vector_type(4)));
typedef __bf16 bf16x8 __attribute__((ext_vector_type(8)));
typedef float floatx4 __attribute__((ext_vector_type(4)));

#define CEXP 0.1803368801111204f  /* (1/8) * log2(e) */

// ---------------------------------------------------------------------------
// Weight pre-convert: fp32 [1024][1024] -> bf16, 4 matrices (Wq,Wk,Wv,Wo)
// ---------------------------------------------------------------------------
__global__ __launch_bounds__(256) void wcvt_kernel(
    const float* __restrict__ Wq, const float* __restrict__ Wk,
    const float* __restrict__ Wv, const float* __restrict__ Wo,
    bf16* __restrict__ dst)
{
  const float* src = (blockIdx.y == 0) ? Wq : (blockIdx.y == 1) ? Wk
                   : (blockIdx.y == 2) ? Wv : Wo;
  bf16* d = dst + (size_t)blockIdx.y * 1048576;
  const int i = (blockIdx.x * 256 + threadIdx.x) * 4;
  const floatx4 v = *(const floatx4*)(src + i);
  bf16x4 o;
#pragma unroll
  for (int j = 0; j < 4; ++j) o[j] = (bf16)v[j];
  *(bf16x4*)(d + i) = o;
}

// ---------------------------------------------------------------------------
// GEMM: C[4096,1024] = A @ Wb(bf16)^T + bias(fp32)
// 128x128 tile, BK=64, 4 waves, register-prefetch pipeline, LDS stride 72.
// Grid is M-MAJOR (x=m,y=n): same-m blocks land on one XCD -> A cached in L2,
// fetched from HBM once (W is tiny and replicated).
// mode 0: A fp32 direct; C bf16 [b,h,s,dk]
// mode 2: A fp32 direct; C bf16 [b,h,dk,s] (transposed V)
// mode 1: A bf16 gathered from Sb [b,h,s,dk]; C fp32 [token][col]
// ---------------------------------------------------------------------------
__device__ __forceinline__ void gemm_body(
    const float* __restrict__ A, const bf16* __restrict__ Ab,
    const bf16* __restrict__ Wb, const float* __restrict__ bias,
    void* __restrict__ Cout, const int mode, const float oscale)
{
  __shared__ __align__(16) bf16 As[128 * 72];
  __shared__ __align__(16) bf16 Bs[128 * 72];
  const int tid  = threadIdx.x;
  const int wave = tid >> 6;
  const int lane = tid & 63;
  const int mlane = lane & 15;
  const int quad  = lane >> 4;
  const int m0 = blockIdx.x * 128;   // m-major grid
  const int n0 = blockIdx.y * 128;
  const int wm = (wave >> 1) * 64;
  const int wn = (wave & 1) * 64;
  const int arow = tid >> 4, ac4 = (tid & 15) * 4;  // fp32 A: 16 rows/pass
  const int wrow = tid >> 3, wc8 = (tid & 7) * 8;   // bf16: 32 rows/pass

  floatx4 a_pf[8];
  bf16x8  ab_pf[4];
  bf16x8  w_pf[4];

  auto load_a = [&](int k0) {
    if (mode == 1) {
#pragma unroll
      for (int c = 0; c < 4; ++c) {
        const int token = m0 + c * 32 + wrow;
        const int b = token >> 11, s = token & 2047;
        const int h = k0 >> 6;  // BK=64 stays within one head
        ab_pf[c] = *(const bf16x8*)(Ab + (((size_t)(b * 16 + h) * 2048 + s) << 6) + wc8);
      }
    } else {
#pragma unroll
      for (int rr = 0; rr < 8; ++rr)
        a_pf[rr] = *(const floatx4*)(A + (size_t)(m0 + rr * 16 + arow) * 1024 + k0 + ac4);
    }
  };
  auto load_w = [&](int k0) {
#pragma unroll
    for (int c = 0; c < 4; ++c)
      w_pf[c] = *(const bf16x8*)(Wb + (size_t)(n0 + c * 32 + wrow) * 1024 + k0 + wc8);
  };

  load_a(0);
  load_w(0);

  floatx4 acc[4][4] = {};

  for (int k0 = 0; k0 < 1024; k0 += 64) {
    if (mode == 1) {
#pragma unroll
      for (int c = 0; c < 4; ++c)
        *(bf16x8*)&As[(c * 32 + wrow) * 72 + wc8] = ab_pf[c];
    } else {
#pragma unroll
      for (int rr = 0; rr < 8; ++rr) {
        bf16x4 ac;
#pragma unroll
        for (int j = 0; j < 4; ++j) ac[j] = (bf16)a_pf[rr][j];
        *(bf16x4*)&As[(rr * 16 + arow) * 72 + ac4] = ac;
      }
    }
#pragma unroll
    for (int c = 0; c < 4; ++c)
      *(bf16x8*)&Bs[(c * 32 + wrow) * 72 + wc8] = w_pf[c];
    __syncthreads();

    if (k0 + 64 < 1024) { load_a(k0 + 64); load_w(k0 + 64); }

#pragma unroll
    for (int kk = 0; kk < 64; kk += 32) {
      bf16x8 af[4], bfr[4];
#pragma unroll
      for (int t = 0; t < 4; ++t) {
        af[t]  = *(const bf16x8*)&As[(wm + t * 16 + mlane) * 72 + kk + quad * 8];
        bfr[t] = *(const bf16x8*)&Bs[(wn + t * 16 + mlane) * 72 + kk + quad * 8];
      }
#pragma unroll
      for (int mt = 0; mt < 4; ++mt)
#pragma unroll
        for (int nt = 0; nt < 4; ++nt)
          acc[mt][nt] = __builtin_amdgcn_mfma_f32_16x16x32_bf16(
              af[mt], bfr[nt], acc[mt][nt], 0, 0, 0);
    }
    __syncthreads();
  }

  // epilogue
#pragma unroll
  for (int nt = 0; nt < 4; ++nt) {
    const int col = n0 + wn + nt * 16 + mlane;
    const float bv = bias[col];
#pragma unroll
    for (int mt = 0; mt < 4; ++mt) {
#pragma unroll
      for (int r = 0; r < 4; ++r) {
        const int row = m0 + wm + mt * 16 + quad * 4 + r;
        const float v = (acc[mt][nt][r] + bv) * oscale;
        if (mode == 0) {
          const int b = row >> 11, s = row & 2047;
          const int h = col >> 6, dk = col & 63;
          ((bf16*)Cout)[(((size_t)(b * 16 + h) * 2048 + s) << 6) + dk] = (bf16)v;
        } else if (mode == 2) {
          const int b = row >> 11, s = row & 2047;
          const int h = col >> 6, dk = col & 63;
          ((bf16*)Cout)[(((size_t)(b * 16 + h) * 64 + dk) << 11) + s] = (bf16)v;
        } else {
          ((float*)Cout)[(size_t)row * 1024 + col] = v;
        }
      }
    }
  }
}

__global__ __launch_bounds__(256) void qkv_kernel(
    const float* __restrict__ q, const float* __restrict__ k, const float* __restrict__ v,
    const bf16* __restrict__ Wb,
    const float* __restrict__ bq, const float* __restrict__ bk, const float* __restrict__ bv,
    bf16* __restrict__ Qw, bf16* __restrict__ Kw, bf16* __restrict__ Vw)
{
  const int z = blockIdx.z;
  const float* A = (z == 0) ? q : (z == 1) ? k : v;
  const bf16* W  = Wb + (size_t)z * 1048576;
  const float* B = (z == 0) ? bq : (z == 1) ? bk : bv;
  if (z == 2)      gemm_body(A, nullptr, W, B, Vw, 2, 1.0f);
  else if (z == 1) gemm_body(A, nullptr, W, B, Kw, 0, 1.0f);
  else             gemm_body(A, nullptr, W, B, Qw, 0, CEXP);
}

__global__ __launch_bounds__(256) void out_kernel(
    const bf16* __restrict__ Sb, const bf16* __restrict__ Wob,
    const float* __restrict__ bo, float* __restrict__ out)
{
  gemm_body(nullptr, Sb, Wob, bo, out, 1, 1.0f);
}

// ---------------------------------------------------------------------------
// Flash attention, no-max softmax. Block = 128 q x 64-key tiles, 4 waves;
// wave owns 32 q (2 subtiles) -> K/V frag reads reused 2x. S^T = K Q^T
// operand-swap: per-lane q=mlane, b64 P stores, per-lane row sums.
// Writes scores fp32 (output) AND bf16 copy (for out_kernel's A-path).
// ---------------------------------------------------------------------------
__global__ __launch_bounds__(256) void attn_kernel(
    const bf16* __restrict__ Qw, const bf16* __restrict__ Kw,
    const bf16* __restrict__ Vtg, float* __restrict__ scores,
    bf16* __restrict__ Sb)
{
  __shared__ __align__(16) bf16 Ks[64 * 72];    // [key][dk]
  __shared__ __align__(16) bf16 Vt[64 * 72];    // [dk][key]
  __shared__ __align__(16) bf16 Ps[4][32 * 72]; // per-wave P [q(32)][key]

  const int tid  = threadIdx.x;
  const int wave = tid >> 6;
  const int lane = tid & 63;
  const int mlane = lane & 15;
  const int quad  = lane >> 4;
  const int bh = blockIdx.y;            // 0..31
  const int q0 = blockIdx.x * 128;
  const size_t base = (size_t)bh << 17; // bh * 2048 * 64

  const int srow = tid >> 3, sc8 = (tid & 7) * 8;

  // Q B-frags (loop-invariant): q = q0 + wave*32 + qt*16 + mlane
  bf16x8 qf[2][2];
#pragma unroll
  for (int qt = 0; qt < 2; ++qt)
#pragma unroll
    for (int c = 0; c < 2; ++c)
      qf[qt][c] = *(const bf16x8*)
          &Qw[base + (size_t)(q0 + wave * 32 + qt * 16 + mlane) * 64 + c * 32 + quad * 8];

  float rs[2] = {0.f, 0.f};
  floatx4 o[2][4] = {};

  bf16x8 kpf[2], vpf[2];
  auto load_kv = [&](int kt) {
#pragma unroll
    for (int rr = 0; rr < 2; ++rr) {
      const int row = rr * 32 + srow;
      kpf[rr] = *(const bf16x8*)&Kw[base + (size_t)(kt + row) * 64 + sc8];
      vpf[rr] = *(const bf16x8*)&Vtg[base + (size_t)row * 2048 + kt + sc8];
    }
  };
  load_kv(0);

  for (int kt = 0; kt < 2048; kt += 64) {
    __syncthreads();
#pragma unroll
    for (int rr = 0; rr < 2; ++rr) {
      const int row = rr * 32 + srow;
      *(bf16x8*)&Ks[row * 72 + sc8] = kpf[rr];
      *(bf16x8*)&Vt[row * 72 + sc8] = vpf[rr];
    }
    __syncthreads();
    if (kt + 64 < 2048) load_kv(kt + 64);

    // S^T = K Q^T ; K-frags shared across both q-subtiles
#pragma unroll
    for (int nt = 0; nt < 4; ++nt) {
      bf16x8 a0 = *(const bf16x8*)&Ks[(nt * 16 + mlane) * 72 + quad * 8];
      bf16x8 a1 = *(const bf16x8*)&Ks[(nt * 16 + mlane) * 72 + 32 + quad * 8];
      floatx4 s0 = {}, s1 = {};
      s0 = __builtin_amdgcn_mfma_f32_16x16x32_bf16(a0, qf[0][0], s0, 0, 0, 0);
      s0 = __builtin_amdgcn_mfma_f32_16x16x32_bf16(a1, qf[0][1], s0, 0, 0, 0);
      s1 = __builtin_amdgcn_mfma_f32_16x16x32_bf16(a0, qf[1][0], s1, 0, 0, 0);
      s1 = __builtin_amdgcn_mfma_f32_16x16x32_bf16(a1, qf[1][1], s1, 0, 0, 0);

      bf16x4 pk0, pk1;
#pragma unroll
      for (int r = 0; r < 4; ++r) {
        const float p0 = exp2f(s0[r]);
        const float p1 = exp2f(s1[r]);
        rs[0] += p0; rs[1] += p1;
        pk0[r] = (bf16)p0; pk1[r] = (bf16)p1;
      }
      *(bf16x4*)&Ps[wave][(mlane)      * 72 + nt * 16 + quad * 4] = pk0;
      *(bf16x4*)&Ps[wave][(16 + mlane) * 72 + nt * 16 + quad * 4] = pk1;
    }

    asm volatile("s_waitcnt lgkmcnt(0)" ::: "memory");

    // O += P V ; V-frags shared across both q-subtiles
#pragma unroll
    for (int c = 0; c < 2; ++c) {
      bf16x8 pa0 = *(const bf16x8*)&Ps[wave][(mlane)      * 72 + c * 32 + quad * 8];
      bf16x8 pa1 = *(const bf16x8*)&Ps[wave][(16 + mlane) * 72 + c * 32 + quad * 8];
#pragma unroll
      for (int nt = 0; nt < 4; ++nt) {
        bf16x8 vb = *(const bf16x8*)&Vt[(nt * 16 + mlane) * 72 + c * 32 + quad * 8];
        o[0][nt] = __builtin_amdgcn_mfma_f32_16x16x32_bf16(pa0, vb, o[0][nt], 0, 0, 0);
        o[1][nt] = __builtin_amdgcn_mfma_f32_16x16x32_bf16(pa1, vb, o[1][nt], 0, 0, 0);
      }
    }
  }

#pragma unroll
  for (int qt = 0; qt < 2; ++qt) {
    rs[qt] += __shfl_xor(rs[qt], 16, 64);
    rs[qt] += __shfl_xor(rs[qt], 32, 64);
  }
  const float inv0 = 1.0f / rs[0];
  const float inv1 = 1.0f / rs[1];

#pragma unroll
  for (int qt = 0; qt < 2; ++qt) {
#pragma unroll
    for (int r = 0; r < 4; ++r) {
      const float invr = __shfl(qt ? inv1 : inv0, quad * 4 + r, 64);
      const int row = q0 + wave * 32 + qt * 16 + quad * 4 + r;
#pragma unroll
      for (int nt = 0; nt < 4; ++nt) {
        const float val = o[qt][nt][r] * invr;
        const size_t idx = base + (size_t)row * 64 + nt * 16 + mlane;
        scores[idx] = val;
        Sb[idx] = (bf16)val;
      }
    }
  }
}

// ---------------------------------------------------------------------------
extern "C" void kernel_launch(void* const* d_in, const int* in_sizes, int n_in,
                              void* d_out, int out_size, void* d_ws, size_t ws_size,
                              hipStream_t stream) {
  const float* query = (const float*)d_in[0];
  const float* key   = (const float*)d_in[1];
  const float* value = (const float*)d_in[2];
  const float* Wq = (const float*)d_in[3];
  const float* bq = (const float*)d_in[4];
  const float* Wk = (const float*)d_in[5];
  const float* bk = (const float*)d_in[6];
  const float* Wv = (const float*)d_in[7];
  const float* bv = (const float*)d_in[8];
  const float* Wo = (const float*)d_in[9];
  const float* bo = (const float*)d_in[10];

  float* out    = (float*)d_out;
  float* scores = out + (size_t)4194304;   // second output (fp32)

  bf16* Wb  = (bf16*)d_ws;                 // 8 MB (Wq,Wk,Wv,Wo bf16)
  bf16* Qws = Wb + (size_t)4194304;        // [b,h,s,dk], pre-scaled by CEXP
  bf16* Kws = Qws + (size_t)4194304;       // [b,h,s,dk]
  bf16* Vws = Kws + (size_t)4194304;       // [b,h,dk,s] (transposed)
  bf16* Sb  = Vws + (size_t)4194304;       // bf16 copy of scores

  wcvt_kernel<<<dim3(1024, 4), 256, 0, stream>>>(Wq, Wk, Wv, Wo, Wb);
  qkv_kernel<<<dim3(32, 8, 3), 256, 0, stream>>>(query, key, value, Wb,
                                                 bq, bk, bv, Qws, Kws, Vws);
  attn_kernel<<<dim3(16, 32), 256, 0, stream>>>(Qws, Kws, Vws, scores, Sb);
  out_kernel<<<dim3(32, 8), 256, 0, stream>>>(Sb, Wb + (size_t)3145728, bo, out);
}